// Round 5
// baseline (1401.252 us; speedup 1.0000x reference)
//
#include <hip/hip_runtime.h>

#define HW 128
#define NPIX 16384      // 128*128
#define CIN 256
#define NSC 147456      // NPIX*9
#define PRENMS 6000
#define POSTK 300
#define DW_CLIP_F 4.135166556742356f
#define MW 96           // u64 words per mask row
typedef unsigned long long ull;

// ---------------------------------------------------------------- zero scratch
__global__ void zero_kernel(unsigned* __restrict__ p, int n) {
    int i = blockIdx.x * 256 + threadIdx.x;
    if (i < n) p[i] = 0u;
}

// ---------------------------------------------------------------- weight transpose
// w: [co=256][k=2304] -> wt: [k=2304][co=256]
__global__ void wt_kernel(const float* __restrict__ w, float* __restrict__ wt) {
    int i = blockIdx.x * 256 + threadIdx.x;
    if (i < 2304 * 256) {
        int k = i >> 8, co = i & 255;
        wt[i] = w[co * 2304 + k];
    }
}

// ---------------------------------------------------------------- 3x3 conv, K-split halves
// feat: [256][128][128], wt: [2304][256], part: [2][256][16384]
// R9 = R1 structure (best measured: 241us) + VECTOR weight loads.
// R0-R4 showed idle ~90-110us invariant to conflicts/blocks-per-CU/barriers/feat-
// prefetch. Shared mechanism in all: weights via s_load (SMEM). SMEM completes
// out-of-order -> waits on weight results force lgkmcnt(0), draining the feat
// ds_read pipeline too; scalar-L1 thrash (4 blocks x 18.4KB > 16KB) puts each
// drain at ~200cy vs 64cy FMA per tap. Fix: load weights through VMEM with a
// uniform address forced into a VGPR (opaque v_mov 0) -> vmcnt-counted, hoisted
// taps ahead; lgkm stream becomes pure-DS (in-order, counted waits).
// Same addresses, same FMA order -> bit-exact.
__global__ __launch_bounds__(256, 4) void conv3x3_half_kernel(
    const float* __restrict__ feat, const float* __restrict__ wt,
    float* __restrict__ part)
{
    __shared__ float in_s[16 * 340];    // 16 ci * (10 rows * 34 floats) = 21760 B
    const int tx = threadIdx.x;         // 0..31
    const int ty = threadIdx.y;         // 0..7
    const int x0 = blockIdx.x * 32;
    const int y0 = blockIdx.y * 8;
    const int h  = blockIdx.z >> 3;
    const int co0 = (blockIdx.z & 7) << 5;
    const int tid = ty * 32 + tx;

    // opaque zero in a VGPR: compiler cannot prove uniformity -> weight loads
    // stay on the vector-memory path (global_load_dwordx4), vmcnt-counted.
    int vzero;
    asm volatile("v_mov_b32 %0, 0" : "=v"(vzero));

    // staging geometry computed ONCE (patch 10 x 34 = 340 entries, 256 threads)
    const int yy1 = tid / 34, xx1 = tid - yy1 * 34;
    const int t2 = tid + 256;
    const int yy2 = t2 / 34, xx2 = t2 - yy2 * 34;
    const int gy1 = y0 + yy1 - 1, gx1 = x0 + xx1 - 1;
    const int gy2 = y0 + yy2 - 1, gx2 = x0 + xx2 - 1;
    const bool p1 = ((unsigned)gy1 < 128u) && ((unsigned)gx1 < 128u);
    const bool p2 = (tid < 84) && ((unsigned)gy2 < 128u) && ((unsigned)gx2 < 128u);
    const int a1 = p1 ? (gy1 * 128 + gx1) : 0;
    const int a2 = p2 ? (gy2 * 128 + gx2) : 0;

    float acc[32];
#pragma unroll
    for (int i = 0; i < 32; ++i) acc[i] = 0.f;

    const float* fh = feat + h * 128 * NPIX;
    const float* wbase = wt + h * 128 * 9 * 256;

    for (int s = 0; s < 8; ++s) {
        __syncthreads();
        const float* fbase = fh + s * 16 * NPIX;
#pragma unroll
        for (int ci = 0; ci < 16; ++ci) {
            float t = fbase[ci * NPIX + a1];
            in_s[ci * 340 + tid] = p1 ? t : 0.f;
        }
        if (tid < 84) {
#pragma unroll
            for (int ci = 0; ci < 16; ++ci) {
                float t = fbase[ci * NPIX + a2];
                in_s[ci * 340 + 256 + tid] = p2 ? t : 0.f;
            }
        }
        __syncthreads();
        const float* ws0 = wbase + s * 16 * 9 * 256 + co0;
#pragma unroll 2
        for (int ci = 0; ci < 16; ++ci) {
            const float* wrow = ws0 + ci * 9 * 256 + vzero;   // VGPR-tainted addr
#pragma unroll
            for (int t = 0; t < 9; ++t) {
                const int ky = t / 3, kx = t - ky * 3;
                float v = in_s[ci * 340 + (ty + ky) * 34 + (tx + kx)];
                const float4* wq = (const float4*)(wrow + t * 256);
                float wv[32];
                *(float4*)&wv[0]  = wq[0];
                *(float4*)&wv[4]  = wq[1];
                *(float4*)&wv[8]  = wq[2];
                *(float4*)&wv[12] = wq[3];
                *(float4*)&wv[16] = wq[4];
                *(float4*)&wv[20] = wq[5];
                *(float4*)&wv[24] = wq[6];
                *(float4*)&wv[28] = wq[7];
#pragma unroll
                for (int co = 0; co < 32; ++co)
                    acc[co] = fmaf(v, wv[co], acc[co]);
            }
        }
    }
    float* po = part + h * (CIN * NPIX) + co0 * NPIX + (y0 + ty) * 128 + (x0 + tx);
#pragma unroll
    for (int co = 0; co < 32; ++co)
        po[co * NPIX] = acc[co];
}

// combine halves + bias + relu, float4 vectorized, in-place on part0 region
__global__ __launch_bounds__(256) void combine_kernel(
    float* __restrict__ part, const float* __restrict__ b)
{
    const int i = blockIdx.x * 256 + threadIdx.x;   // 1,048,576 float4s
    float4 a = ((const float4*)part)[i];
    float4 c = ((const float4*)(part + CIN * NPIX))[i];
    float bias = b[i >> 12];                         // 4096 float4s per channel
    float4 r;
    r.x = fmaxf(a.x + c.x + bias, 0.f);
    r.y = fmaxf(a.y + c.y + bias, 0.f);
    r.z = fmaxf(a.z + c.z + bias, 0.f);
    r.w = fmaxf(a.w + c.w + bias, 0.f);
    ((float4*)part)[i] = r;
}

// ---------------------------------------------------------------- 1x1 heads: cls(9) + bbox(36)
// 4 waves/block, each wave owns a 12-slot slice of the 45 outputs (ci-sum
// order per output unchanged -> bit-exact). 1024 waves = 4/CU.
__global__ __launch_bounds__(256) void heads_kernel(
    const float* __restrict__ rf,
    const float* __restrict__ cls_w, const float* __restrict__ cls_b,
    const float* __restrict__ bbox_w, const float* __restrict__ bbox_b,
    float* __restrict__ scores, float* __restrict__ bb)
{
    __shared__ float wl[256][48];   // [ci][slot], 0-8 = cls, 9-44 = bbox, 45-47 = 0
    const int tid = threadIdx.x;
    for (int e = tid; e < 256 * 48; e += 256) {
        int ci = e / 48, s = e - ci * 48;
        wl[ci][s] = (s < 9) ? cls_w[s * CIN + ci]
                  : (s < 45) ? bbox_w[(s - 9) * CIN + ci] : 0.f;
    }
    __syncthreads();

    const int lane = tid & 63;
    const int sg   = tid >> 6;          // slot group 0..3
    const int p    = blockIdx.x * 64 + lane;
    const int s0   = sg * 12;
    const int ns   = (sg == 3) ? 9 : 12;

    float acc[12];
#pragma unroll
    for (int i = 0; i < 12; ++i) acc[i] = 0.f;

#pragma unroll 4
    for (int ci = 0; ci < CIN; ++ci) {
        float v = rf[ci * NPIX + p];
        const float* wr = &wl[ci][s0];
#pragma unroll
        for (int j = 0; j < 12; ++j)
            acc[j] = fmaf(v, wr[j], acc[j]);
    }
    for (int j = 0; j < ns; ++j) {
        int s = s0 + j;
        if (s < 9) {
            float sc = acc[j] + cls_b[s];
            scores[p * 9 + s] = 1.0f / (1.0f + expf(-sc));
        } else {
            bb[(s - 9) * NPIX + p] = acc[j] + bbox_b[s - 9];
        }
    }
}

// ---------------------------------------------------------------- top-k select: histograms
__global__ __launch_bounds__(1024) void hist1_kernel(const float* __restrict__ scores,
                                                     unsigned* __restrict__ hist1) {
    __shared__ unsigned h[16384];
    const int tid = threadIdx.x;
    for (int i = tid; i < 16384; i += 1024) h[i] = 0u;
    __syncthreads();
    for (int i = blockIdx.x * 1024 + tid; i < NSC; i += gridDim.x * 1024) {
        unsigned bits = __float_as_uint(scores[i]);
        atomicAdd(&h[bits >> 16], 1u);
    }
    __syncthreads();
    for (int i = tid; i < 16384; i += 1024) {
        unsigned c = h[i];
        if (c) atomicAdd(&hist1[i], c);
    }
}

__global__ __launch_bounds__(1024) void scan1_kernel(const unsigned* __restrict__ hist,
                                                     unsigned* __restrict__ meta) {
    __shared__ unsigned ssum[1024];
    const int t = threadIdx.x;
    unsigned local[16];
    unsigned s = 0;
#pragma unroll
    for (int i = 0; i < 16; ++i) { local[i] = hist[t * 16 + i]; s += local[i]; }
    ssum[t] = s;
    __syncthreads();
    for (int off = 1; off < 1024; off <<= 1) {
        unsigned v = ssum[t] + ((t + off < 1024) ? ssum[t + off] : 0u);
        __syncthreads();
        ssum[t] = v;
        __syncthreads();
    }
    unsigned run = ssum[t] - s;
#pragma unroll
    for (int i = 15; i >= 0; --i) {
        unsigned nb = run + local[i];
        if (nb >= (unsigned)PRENMS && run < (unsigned)PRENMS) {
            meta[1] = (unsigned)(t * 16 + i);
            meta[2] = run;
        }
        run = nb;
    }
}

__global__ void hist2_kernel(const float* __restrict__ scores, const unsigned* __restrict__ meta,
                             unsigned* __restrict__ hist2) {
    int i = blockIdx.x * 256 + threadIdx.x;
    if (i < NSC) {
        unsigned bits = __float_as_uint(scores[i]);
        if ((bits >> 16) == meta[1]) atomicAdd(&hist2[bits & 0xFFFFu], 1u);
    }
}

__global__ __launch_bounds__(1024) void scan2_kernel(const unsigned* __restrict__ hist2,
                                                     unsigned* __restrict__ meta) {
    __shared__ unsigned ssum[1024];
    const int t = threadIdx.x;
    const unsigned need = (unsigned)PRENMS - meta[2];
    unsigned s = 0;
    for (int i = 0; i < 64; ++i) s += hist2[t * 64 + i];
    ssum[t] = s;
    __syncthreads();
    for (int off = 1; off < 1024; off <<= 1) {
        unsigned v = ssum[t] + ((t + off < 1024) ? ssum[t + off] : 0u);
        __syncthreads();
        ssum[t] = v;
        __syncthreads();
    }
    unsigned run = ssum[t] - s;
    for (int i = 63; i >= 0; --i) {
        unsigned h = hist2[t * 64 + i];
        unsigned nb = run + h;
        if (nb >= need && run < need) {
            meta[3] = (meta[1] << 16) | (unsigned)(t * 64 + i);
        }
        run = nb;
    }
}

// wave-aggregated compaction: 1 atomic per wave
__global__ void compact_kernel(const float* __restrict__ scores, unsigned* __restrict__ meta,
                               ull* __restrict__ cand) {
    int i = blockIdx.x * 256 + threadIdx.x;
    unsigned bits = (i < NSC) ? __float_as_uint(scores[i]) : 0u;
    bool pred = (i < NSC) && (bits >= meta[3]);
    ull bal = __ballot(pred);
    int lane = threadIdx.x & 63;
    unsigned cnt = (unsigned)__popcll(bal);
    unsigned base = 0;
    if (lane == 0 && cnt) base = atomicAdd(&meta[0], cnt);
    base = __shfl(base, 0);
    if (pred) {
        unsigned off = (unsigned)__popcll(bal & ((1ull << lane) - 1ull));
        unsigned pos = base + off;
        if (pos < 8192u)
            cand[pos] = ((ull)bits << 32) | (unsigned)(~i);
    }
}

// ---------------------------------------------------------------- parallel sort: 4 local sorts + rank-merge
__global__ __launch_bounds__(1024) void sortA_kernel(const ull* __restrict__ cand,
                                                     const unsigned* __restrict__ meta,
                                                     ull* __restrict__ sorted) {
    __shared__ ull keys[2048];
    const int tid = threadIdx.x;
    const int base = blockIdx.x * 2048;
    const int n = min((int)meta[0], 8192);
    for (int i = tid; i < 2048; i += 1024) {
        int g = base + i;
        keys[i] = (g < n) ? cand[g] : (ull)(8191 - g);
    }
    __syncthreads();
    for (int k = 2; k <= 2048; k <<= 1) {
        for (int j = k >> 1; j >= 1; j >>= 1) {
            int s = tid;
            int i = ((s & ~(j - 1)) << 1) | (s & (j - 1));
            int p = i | j;
            ull a = keys[i], c = keys[p];
            bool desc = ((i & k) == 0);
            bool sw = desc ? (a < c) : (a > c);
            if (sw) { keys[i] = c; keys[p] = a; }
            __syncthreads();
        }
    }
    for (int i = tid; i < 2048; i += 1024) sorted[base + i] = keys[i];
}

__global__ __launch_bounds__(256) void merge_kernel(const ull* __restrict__ sorted,
                                                    ull* __restrict__ fin) {
    const int g = blockIdx.x * 256 + threadIdx.x;   // 32 blocks -> 8192
    ull x = sorted[g];
    const int c = g >> 11;
    int rank = g & 2047;
#pragma unroll
    for (int cc = 0; cc < 4; ++cc) {
        if (cc == c) continue;
        const ull* arr = sorted + cc * 2048;
        int lo = 0, hi = 2048;
        while (lo < hi) { int mid = (lo + hi) >> 1; if (arr[mid] > x) lo = mid + 1; else hi = mid; }
        rank += lo;
    }
    fin[rank] = x;
}

// ---------------------------------------------------------------- decode top-6000 (parallel)
__global__ __launch_bounds__(64) void decode_kernel(
    const ull* __restrict__ fin, const float* __restrict__ bb,
    float* __restrict__ selbox, float* __restrict__ selsc,
    ull* __restrict__ validbits)
{
    const int r = blockIdx.x * 64 + threadIdx.x;
    int valid = 0;
    if (r < PRENMS) {
        ull key = fin[r];
        unsigned sbits = (unsigned)(key >> 32);
        unsigned idx = ~(unsigned)(key & 0xFFFFFFFFull);
        float score = __uint_as_float(sbits);
        int p = (int)(idx / 9u);
        int a = (int)(idx - (unsigned)p * 9u);
        int y = p >> 7, x = p & 127;
        float d0 = bb[(a * 4 + 0) * NPIX + p];
        float d1 = bb[(a * 4 + 1) * NPIX + p];
        float d2 = bb[(a * 4 + 2) * NPIX + p];
        float d3 = bb[(a * 4 + 3) * NPIX + p];
        int ar_i = a / 3, sc_i = a - ar_i * 3;
        float arv = (ar_i == 0) ? 0.5f : ((ar_i == 1) ? 1.0f : 2.0f);
        float scv = (sc_i == 0) ? 128.f : ((sc_i == 1) ? 256.f : 512.f);
        float hr = sqrtf(arv);
        float wr = 1.0f / hr;
        float hs = hr * scv;
        float wsv = wr * scv;
        float bx1 = rintf(-wsv * 0.5f), by1 = rintf(-hs * 0.5f);
        float bx2 = rintf(wsv * 0.5f),  by2 = rintf(hs * 0.5f);
        float ax1 = x * 8.f + bx1, ay1 = y * 8.f + by1;
        float ax2 = x * 8.f + bx2, ay2 = y * 8.f + by2;
        float wa = ax2 - ax1, ha = ay2 - ay1;
        float cx = ax1 + 0.5f * wa, cy = ay1 + 0.5f * ha;
        float dw = fminf(d2, DW_CLIP_F), dh = fminf(d3, DW_CLIP_F);
        float px = d0 * wa + cx, py = d1 * ha + cy;
        float pw = expf(dw) * wa, ph = expf(dh) * ha;
        float x1 = px - 0.5f * pw, y1 = py - 0.5f * ph;
        float x2 = px + 0.5f * pw, y2 = py + 0.5f * ph;
        x1 = fminf(fmaxf(x1, 0.f), 1024.f);
        y1 = fminf(fmaxf(y1, 0.f), 1024.f);
        x2 = fminf(fmaxf(x2, 0.f), 1024.f);
        y2 = fminf(fmaxf(y2, 0.f), 1024.f);
        float bw = x2 - x1, bh = y2 - y1;
        valid = (bw >= 16.f) && (bh >= 16.f);
        selbox[r * 4 + 0] = x1; selbox[r * 4 + 1] = y1;
        selbox[r * 4 + 2] = x2; selbox[r * 4 + 3] = y2;
        selsc[r] = score;
    }
    ull bal = __ballot(valid);
    if (threadIdx.x == 0) validbits[blockIdx.x] = bal;
}

// ---------------------------------------------------------------- IOU suppression mask build
__global__ __launch_bounds__(256) void maskbuild_kernel(
    const float* __restrict__ selbox, ull* __restrict__ mask)
{
    __shared__ float jb0[64], jb1[64], jb2[64], jb3[64];
    const int jw = blockIdx.y;
    const int tid = threadIdx.x;
    const int i = blockIdx.x * 256 + tid;
    if (jw * 64 + 63 < blockIdx.x * 256) {
        if (i < PRENMS) mask[(size_t)i * MW + jw] = 0ull;
        return;
    }
    if (tid < 64) {
        int j = jw * 64 + tid;
        float x1 = 0.f, y1 = 0.f, x2 = 0.f, y2 = 0.f;
        if (j < PRENMS) {
            x1 = selbox[j * 4 + 0]; y1 = selbox[j * 4 + 1];
            x2 = selbox[j * 4 + 2]; y2 = selbox[j * 4 + 3];
        }
        jb0[tid] = x1; jb1[tid] = y1; jb2[tid] = x2; jb3[tid] = y2;
    }
    __syncthreads();
    if (i >= PRENMS) return;
    const float ix1 = selbox[i * 4 + 0], iy1 = selbox[i * 4 + 1];
    const float ix2 = selbox[i * 4 + 2], iy2 = selbox[i * 4 + 3];
    const float iarea = (ix2 - ix1) * (iy2 - iy1);
    ull word = 0ull;
    for (int b = 0; b < 64; ++b) {
        int j = jw * 64 + b;
        float xx1 = fmaxf(ix1, jb0[b]);
        float yy1 = fmaxf(iy1, jb1[b]);
        float xx2 = fminf(ix2, jb2[b]);
        float yy2 = fminf(iy2, jb3[b]);
        float iw = fmaxf(xx2 - xx1, 0.f);
        float ih = fmaxf(yy2 - yy1, 0.f);
        float inter = iw * ih;
        float jarea = (jb2[b] - jb0[b]) * (jb3[b] - jb1[b]);
        float iou = inter / (iarea + jarea - inter);
        if (j > i && iou > 0.7f) word |= (1ull << b);
    }
    mask[(size_t)i * MW + jw] = word;
}

// ---------------------------------------------------------------- chunked single-wave greedy NMS
__global__ __launch_bounds__(64) void nms_scan_kernel(
    const ull* __restrict__ validbits,
    const ull* __restrict__ mask,
    const float* __restrict__ selbox, const float* __restrict__ selsc,
    float* __restrict__ out)
{
    __shared__ int kept[POSTK];
    const int l = threadIdx.x;
    ull supp0 = ~validbits[l];
    ull supp1 = (l < 30) ? ~validbits[64 + l] : ~0ull;
    int nk = 0;
    ull ownrow_next = mask[(size_t)l * MW + 0];
    for (int wi = 0; wi < 94 && nk < POSTK; ++wi) {
        ull ownrow = ownrow_next;
        if (wi < 93) ownrow_next = mask[(size_t)((wi + 1) * 64 + l) * MW + (wi + 1)];
        ull wsup = (wi < 64) ? __shfl(supp0, wi) : __shfl(supp1, wi - 64);
        ull active = ~wsup;
        if (!active) continue;
        ull keptbits = 0ull;
        while (active && nk < POSTK) {
            int b = __builtin_ctzll(active);
            keptbits |= (1ull << b);
            if (l == 0) kept[nk] = wi * 64 + b;
            nk++;
            ull rowb = __shfl(ownrow, b);
            ull gt = (b == 63) ? 0ull : (~0ull << (b + 1));
            active &= gt & ~rowb;
        }
        while (keptbits) {
            int b0 = __builtin_ctzll(keptbits); keptbits &= keptbits - 1;
            int b1 = -1, b2 = -1, b3 = -1;
            if (keptbits) { b1 = __builtin_ctzll(keptbits); keptbits &= keptbits - 1; }
            if (keptbits) { b2 = __builtin_ctzll(keptbits); keptbits &= keptbits - 1; }
            if (keptbits) { b3 = __builtin_ctzll(keptbits); keptbits &= keptbits - 1; }
            const ull* r0 = mask + (size_t)(wi * 64 + b0) * MW;
            ull t0a = r0[l], t0b = (l < 30) ? r0[64 + l] : 0ull;
            ull t1a = 0, t1b = 0, t2a = 0, t2b = 0, t3a = 0, t3b = 0;
            if (b1 >= 0) { const ull* r1 = mask + (size_t)(wi * 64 + b1) * MW; t1a = r1[l]; t1b = (l < 30) ? r1[64 + l] : 0ull; }
            if (b2 >= 0) { const ull* r2 = mask + (size_t)(wi * 64 + b2) * MW; t2a = r2[l]; t2b = (l < 30) ? r2[64 + l] : 0ull; }
            if (b3 >= 0) { const ull* r3 = mask + (size_t)(wi * 64 + b3) * MW; t3a = r3[l]; t3b = (l < 30) ? r3[64 + l] : 0ull; }
            supp0 |= t0a | t1a | t2a | t3a;
            supp1 |= t0b | t1b | t2b | t3b;
        }
    }
    __syncthreads();
    for (int r = l; r < POSTK; r += 64) {
        if (r < nk) {
            int i = kept[r];
            out[r * 5 + 0] = selbox[i * 4 + 0];
            out[r * 5 + 1] = selbox[i * 4 + 1];
            out[r * 5 + 2] = selbox[i * 4 + 2];
            out[r * 5 + 3] = selbox[i * 4 + 3];
            out[r * 5 + 4] = selsc[i];
        } else {
            out[r * 5 + 0] = 0.f; out[r * 5 + 1] = 0.f;
            out[r * 5 + 2] = 0.f; out[r * 5 + 3] = 0.f;
            out[r * 5 + 4] = 0.f;
        }
    }
}

// ---------------------------------------------------------------- launch
extern "C" void kernel_launch(void* const* d_in, const int* in_sizes, int n_in,
                              void* d_out, int out_size, void* d_ws, size_t ws_size,
                              hipStream_t stream) {
    const float* feat    = (const float*)d_in[1];
    const float* conv_w  = (const float*)d_in[2];
    const float* conv_b  = (const float*)d_in[3];
    const float* cls_w   = (const float*)d_in[4];
    const float* cls_b   = (const float*)d_in[5];
    const float* bbox_w  = (const float*)d_in[6];
    const float* bbox_b  = (const float*)d_in[7];
    float* out = (float*)d_out;

    char* ws = (char*)d_ws;
    float*    part      = (float*)(ws + 0);                 // 33,554,432 (2 halves; half0 becomes rpn_feat)
    float*    rpn_feat  = part;                             // alias after combine
    float*    wt        = (float*)(ws + 33554432);          //  2,359,296
    float*    bb        = (float*)(ws + 35913728);          //  2,359,296
    float*    scores    = (float*)(ws + 38273024);          //    589,824
    unsigned* hist1     = (unsigned*)(ws + 38862848);       //     65,536
    unsigned* hist2     = (unsigned*)(ws + 38928384);       //    262,144
    unsigned* meta      = (unsigned*)(ws + 39190528);       //        256
    ull*      cand      = (ull*)(ws + 39190784);            //     65,536
    ull*      sorted    = (ull*)(ws + 39256320);            //     65,536
    ull*      fin       = (ull*)(ws + 39321856);            //     65,536
    float*    selbox    = (float*)(ws + 39387392);          //     96,256
    float*    selsc     = (float*)(ws + 39483648);          //     24,064
    ull*      validbits = (ull*)(ws + 39507712);            //        768
    ull*      mask      = (ull*)(ws + 39508480);            //  4,608,000  -> total 44,116,480

    {
        int nz = 16384 + 65536 + 64;  // hist1 + hist2 + meta contiguous
        zero_kernel<<<(nz + 255) / 256, 256, 0, stream>>>(hist1, nz);
    }
    wt_kernel<<<(2304 * 256 + 255) / 256, 256, 0, stream>>>(conv_w, wt);
    conv3x3_half_kernel<<<dim3(4, 16, 16), dim3(32, 8), 0, stream>>>(feat, wt, part);
    combine_kernel<<<4096, 256, 0, stream>>>(part, conv_b);
    heads_kernel<<<256, 256, 0, stream>>>(rpn_feat, cls_w, cls_b, bbox_w, bbox_b, scores, bb);
    hist1_kernel<<<64, 1024, 0, stream>>>(scores, hist1);
    scan1_kernel<<<1, 1024, 0, stream>>>(hist1, meta);
    hist2_kernel<<<(NSC + 255) / 256, 256, 0, stream>>>(scores, meta, hist2);
    scan2_kernel<<<1, 1024, 0, stream>>>(hist2, meta);
    compact_kernel<<<(NSC + 255) / 256, 256, 0, stream>>>(scores, meta, cand);
    sortA_kernel<<<4, 1024, 0, stream>>>(cand, meta, sorted);
    merge_kernel<<<32, 256, 0, stream>>>(sorted, fin);
    decode_kernel<<<94, 64, 0, stream>>>(fin, bb, selbox, selsc, validbits);
    maskbuild_kernel<<<dim3(24, 94), 256, 0, stream>>>(selbox, mask);
    nms_scan_kernel<<<1, 64, 0, stream>>>(validbits, mask, selbox, selsc, out);
}

// Round 6
// 698.175 us; speedup vs baseline: 2.0070x; 2.0070x over previous
//
#include <hip/hip_runtime.h>
#include <hip/hip_cooperative_groups.h>

namespace cg = cooperative_groups;

#define HW 128
#define NPIX 16384      // 128*128
#define CIN 256
#define NSC 147456      // NPIX*9
#define PRENMS 6000
#define POSTK 300
#define DW_CLIP_F 4.135166556742356f
#define MW 96           // u64 words per mask row
typedef unsigned long long ull;

// ---------------------------------------------------------------- weight transpose
// w: [co=256][k=2304] -> wt: [k=2304][co=256]
__global__ void wt_kernel(const float* __restrict__ w, float* __restrict__ wt) {
    int i = blockIdx.x * 256 + threadIdx.x;
    if (i < 2304 * 256) {
        int k = i >> 8, co = i & 255;
        wt[i] = w[co * 2304 + k];
    }
}

// ---------------------------------------------------------------- 3x3 conv, K-split halves
// EXACT R1 structure (best measured: 241us, VALUBusy 62%, conflicts 0, bit-exact).
// 32x8 spatial tile, 34-float row stride, co=32 per block, ci-chunk 16,
// s_load (SMEM) weight path. R2/R4/R5 experiments all regressed -- this is the
// empirical optimum of the explored conv space.
__global__ __launch_bounds__(256) void conv3x3_half_kernel(
    const float* __restrict__ feat, const float* __restrict__ wt,
    float* __restrict__ part)
{
    __shared__ float in_s[16 * 340];    // 16 ci * (10 rows * 34 floats) = 21760 B
    const int tx = threadIdx.x;         // 0..31
    const int ty = threadIdx.y;         // 0..7
    const int x0 = blockIdx.x * 32;
    const int y0 = blockIdx.y * 8;
    const int h  = blockIdx.z >> 3;
    const int co0 = (blockIdx.z & 7) << 5;
    const int tid = ty * 32 + tx;

    // staging geometry computed ONCE (patch 10 x 34 = 340 entries, 256 threads)
    const int yy1 = tid / 34, xx1 = tid - yy1 * 34;
    const int t2 = tid + 256;
    const int yy2 = t2 / 34, xx2 = t2 - yy2 * 34;
    const int gy1 = y0 + yy1 - 1, gx1 = x0 + xx1 - 1;
    const int gy2 = y0 + yy2 - 1, gx2 = x0 + xx2 - 1;
    const bool p1 = ((unsigned)gy1 < 128u) && ((unsigned)gx1 < 128u);
    const bool p2 = (tid < 84) && ((unsigned)gy2 < 128u) && ((unsigned)gx2 < 128u);
    const int a1 = p1 ? (gy1 * 128 + gx1) : 0;
    const int a2 = p2 ? (gy2 * 128 + gx2) : 0;

    float acc[32];
#pragma unroll
    for (int i = 0; i < 32; ++i) acc[i] = 0.f;

    const float* fh = feat + h * 128 * NPIX;
    const float* wh = wt + h * 128 * 9 * 256;

    for (int s = 0; s < 8; ++s) {
        __syncthreads();
        const float* fbase = fh + s * 16 * NPIX;
#pragma unroll
        for (int ci = 0; ci < 16; ++ci) {
            float t = fbase[ci * NPIX + a1];
            in_s[ci * 340 + tid] = p1 ? t : 0.f;
        }
        if (tid < 84) {
#pragma unroll
            for (int ci = 0; ci < 16; ++ci) {
                float t = fbase[ci * NPIX + a2];
                in_s[ci * 340 + 256 + tid] = p2 ? t : 0.f;
            }
        }
        __syncthreads();
        const float* ws0 = wh + s * 16 * 9 * 256 + co0;
#pragma unroll 2
        for (int ci = 0; ci < 16; ++ci) {
            const float* wrow = ws0 + ci * 9 * 256;
#pragma unroll
            for (int t = 0; t < 9; ++t) {
                const int ky = t / 3, kx = t - ky * 3;
                float v = in_s[ci * 340 + (ty + ky) * 34 + (tx + kx)];
                const float* wp = wrow + t * 256;   // wave-uniform -> s_load_dwordx16
#pragma unroll
                for (int co = 0; co < 32; ++co)
                    acc[co] = fmaf(v, wp[co], acc[co]);
            }
        }
    }
    float* po = part + h * (CIN * NPIX) + co0 * NPIX + (y0 + ty) * 128 + (x0 + tx);
#pragma unroll
    for (int co = 0; co < 32; ++co)
        po[co * NPIX] = acc[co];
}

// combine halves + bias + relu, float4 vectorized, in-place on part0 region
__global__ __launch_bounds__(256) void combine_kernel(
    float* __restrict__ part, const float* __restrict__ b)
{
    const int i = blockIdx.x * 256 + threadIdx.x;   // 1,048,576 float4s
    float4 a = ((const float4*)part)[i];
    float4 c = ((const float4*)(part + CIN * NPIX))[i];
    float bias = b[i >> 12];                         // 4096 float4s per channel
    float4 r;
    r.x = fmaxf(a.x + c.x + bias, 0.f);
    r.y = fmaxf(a.y + c.y + bias, 0.f);
    r.z = fmaxf(a.z + c.z + bias, 0.f);
    r.w = fmaxf(a.w + c.w + bias, 0.f);
    ((float4*)part)[i] = r;
}

// ---------------------------------------------------------------- 1x1 heads: cls(9) + bbox(36)
// 4 waves/block, each wave owns a 12-slot slice of the 45 outputs (ci-sum
// order per output unchanged -> bit-exact). 1024 waves = 4/CU.
__global__ __launch_bounds__(256) void heads_kernel(
    const float* __restrict__ rf,
    const float* __restrict__ cls_w, const float* __restrict__ cls_b,
    const float* __restrict__ bbox_w, const float* __restrict__ bbox_b,
    float* __restrict__ scores, float* __restrict__ bb)
{
    __shared__ float wl[256][48];   // [ci][slot], 0-8 = cls, 9-44 = bbox, 45-47 = 0
    const int tid = threadIdx.x;
    for (int e = tid; e < 256 * 48; e += 256) {
        int ci = e / 48, s = e - ci * 48;
        wl[ci][s] = (s < 9) ? cls_w[s * CIN + ci]
                  : (s < 45) ? bbox_w[(s - 9) * CIN + ci] : 0.f;
    }
    __syncthreads();

    const int lane = tid & 63;
    const int sg   = tid >> 6;          // slot group 0..3
    const int p    = blockIdx.x * 64 + lane;
    const int s0   = sg * 12;
    const int ns   = (sg == 3) ? 9 : 12;

    float acc[12];
#pragma unroll
    for (int i = 0; i < 12; ++i) acc[i] = 0.f;

#pragma unroll 4
    for (int ci = 0; ci < CIN; ++ci) {
        float v = rf[ci * NPIX + p];
        const float* wr = &wl[ci][s0];
#pragma unroll
        for (int j = 0; j < 12; ++j)
            acc[j] = fmaf(v, wr[j], acc[j]);
    }
    for (int j = 0; j < ns; ++j) {
        int s = s0 + j;
        if (s < 9) {
            float sc = acc[j] + cls_b[s];
            scores[p * 9 + s] = 1.0f / (1.0f + expf(-sc));
        } else {
            bb[(s - 9) * NPIX + p] = acc[j] + bbox_b[s - 9];
        }
    }
}

// ---------------------------------------------------------------- fused top-k select (cooperative)
// Replaces 8 dispatches: zero, hist1, scan1, hist2, scan2, compact, sortA, merge.
// 64 blocks x 1024 threads, 64KB LDS -> 2 blocks/CU capacity, co-residency 64<=512 OK.
// Each phase's arithmetic is verbatim from the standalone kernels -> bit-exact.
// hist1/hist2/meta are CONTIGUOUS in the workspace (zeroed via hist1 pointer).
__global__ __launch_bounds__(1024) void select_kernel(
    const float* __restrict__ scores,
    unsigned* __restrict__ hist1, unsigned* __restrict__ hist2,
    unsigned* __restrict__ meta, ull* __restrict__ cand,
    ull* __restrict__ sorted, ull* __restrict__ fin)
{
    cg::grid_group grid = cg::this_grid();
    __shared__ __align__(16) unsigned sh[16384];    // 64KB, reused across phases
    const int tid  = threadIdx.x;
    const int gtid = blockIdx.x * 1024 + tid;
    const int gsz  = gridDim.x * 1024;              // 65536

    // ---- phase 0: zero global hist1+hist2+meta, build per-block LDS histogram
    for (int i = gtid; i < 16384 + 65536 + 64; i += gsz) hist1[i] = 0u;
    for (int i = tid; i < 16384; i += 1024) sh[i] = 0u;
    __syncthreads();
    for (int i = gtid; i < NSC; i += gsz) {
        unsigned bits = __float_as_uint(scores[i]);
        atomicAdd(&sh[bits >> 16], 1u);
    }
    __syncthreads();
    __threadfence();
    grid.sync();

    // ---- phase 1: merge LDS histograms into global hist1
    for (int i = tid; i < 16384; i += 1024) {
        unsigned c = sh[i];
        if (c) atomicAdd(&hist1[i], c);
    }
    __threadfence();
    grid.sync();

    // ---- phase 2: scan1 (block 0 only; verbatim scan1_kernel body, ssum -> sh)
    if (blockIdx.x == 0) {
        unsigned* ssum = sh;
        const int t = tid;
        unsigned local[16];
        unsigned s = 0;
#pragma unroll
        for (int i = 0; i < 16; ++i) { local[i] = hist1[t * 16 + i]; s += local[i]; }
        ssum[t] = s;
        __syncthreads();
        for (int off = 1; off < 1024; off <<= 1) {
            unsigned v = ssum[t] + ((t + off < 1024) ? ssum[t + off] : 0u);
            __syncthreads();
            ssum[t] = v;
            __syncthreads();
        }
        unsigned run = ssum[t] - s;
#pragma unroll
        for (int i = 15; i >= 0; --i) {
            unsigned nb = run + local[i];
            if (nb >= (unsigned)PRENMS && run < (unsigned)PRENMS) {
                meta[1] = (unsigned)(t * 16 + i);
                meta[2] = run;
            }
            run = nb;
        }
    }
    __threadfence();
    grid.sync();

    // ---- phase 3: hist2
    {
        const unsigned m1 = meta[1];
        for (int i = gtid; i < NSC; i += gsz) {
            unsigned bits = __float_as_uint(scores[i]);
            if ((bits >> 16) == m1) atomicAdd(&hist2[bits & 0xFFFFu], 1u);
        }
    }
    __threadfence();
    grid.sync();

    // ---- phase 4: scan2 (block 0 only; verbatim scan2_kernel body)
    if (blockIdx.x == 0) {
        unsigned* ssum = sh;
        const int t = tid;
        const unsigned need = (unsigned)PRENMS - meta[2];
        unsigned s = 0;
        for (int i = 0; i < 64; ++i) s += hist2[t * 64 + i];
        ssum[t] = s;
        __syncthreads();
        for (int off = 1; off < 1024; off <<= 1) {
            unsigned v = ssum[t] + ((t + off < 1024) ? ssum[t + off] : 0u);
            __syncthreads();
            ssum[t] = v;
            __syncthreads();
        }
        unsigned run = ssum[t] - s;
        for (int i = 63; i >= 0; --i) {
            unsigned h = hist2[t * 64 + i];
            unsigned nb = run + h;
            if (nb >= need && run < need) {
                meta[3] = (meta[1] << 16) | (unsigned)(t * 64 + i);
            }
            run = nb;
        }
    }
    __threadfence();
    grid.sync();

    // ---- phase 5: compact (wave-aggregated, 1 atomic per wave)
    {
        const unsigned thr = meta[3];
        for (int base = blockIdx.x * 1024; base < NSC; base += gsz) {
            int i = base + tid;
            unsigned bits = (i < NSC) ? __float_as_uint(scores[i]) : 0u;
            bool pred = (i < NSC) && (bits >= thr);
            ull bal = __ballot(pred);
            int lane = tid & 63;
            unsigned cnt = (unsigned)__popcll(bal);
            unsigned bse = 0;
            if (lane == 0 && cnt) bse = atomicAdd(&meta[0], cnt);
            bse = __shfl(bse, 0);
            if (pred) {
                unsigned off = (unsigned)__popcll(bal & ((1ull << lane) - 1ull));
                unsigned pos = bse + off;
                if (pos < 8192u)
                    cand[pos] = ((ull)bits << 32) | (unsigned)(~i);
            }
        }
    }
    __threadfence();
    grid.sync();

    // ---- phase 6: bitonic sort of 4x 2048 segments (blocks 0..3; verbatim sortA)
    if (blockIdx.x < 4) {
        ull* keys = (ull*)sh;   // 16KB of the 64KB
        const int base = blockIdx.x * 2048;
        const int n = min((int)meta[0], 8192);
        for (int i = tid; i < 2048; i += 1024) {
            int g = base + i;
            keys[i] = (g < n) ? cand[g] : (ull)(8191 - g);
        }
        __syncthreads();
        for (int k = 2; k <= 2048; k <<= 1) {
            for (int j = k >> 1; j >= 1; j >>= 1) {
                int s = tid;
                int i = ((s & ~(j - 1)) << 1) | (s & (j - 1));
                int p = i | j;
                ull a = keys[i], c = keys[p];
                bool desc = ((i & k) == 0);
                bool sw = desc ? (a < c) : (a > c);
                if (sw) { keys[i] = c; keys[p] = a; }
                __syncthreads();
            }
        }
        for (int i = tid; i < 2048; i += 1024) sorted[base + i] = keys[i];
    }
    __threadfence();
    grid.sync();

    // ---- phase 7: rank-merge (first 8192 threads; verbatim merge_kernel)
    if (gtid < 8192) {
        const int g = gtid;
        ull x = sorted[g];
        const int c = g >> 11;
        int rank = g & 2047;
#pragma unroll
        for (int cc = 0; cc < 4; ++cc) {
            if (cc == c) continue;
            const ull* arr = sorted + cc * 2048;
            int lo = 0, hi = 2048;
            while (lo < hi) { int mid = (lo + hi) >> 1; if (arr[mid] > x) lo = mid + 1; else hi = mid; }
            rank += lo;
        }
        fin[rank] = x;
    }
}

// ---------------------------------------------------------------- decode top-6000 (parallel)
__global__ __launch_bounds__(64) void decode_kernel(
    const ull* __restrict__ fin, const float* __restrict__ bb,
    float* __restrict__ selbox, float* __restrict__ selsc,
    ull* __restrict__ validbits)
{
    const int r = blockIdx.x * 64 + threadIdx.x;
    int valid = 0;
    if (r < PRENMS) {
        ull key = fin[r];
        unsigned sbits = (unsigned)(key >> 32);
        unsigned idx = ~(unsigned)(key & 0xFFFFFFFFull);
        float score = __uint_as_float(sbits);
        int p = (int)(idx / 9u);
        int a = (int)(idx - (unsigned)p * 9u);
        int y = p >> 7, x = p & 127;
        float d0 = bb[(a * 4 + 0) * NPIX + p];
        float d1 = bb[(a * 4 + 1) * NPIX + p];
        float d2 = bb[(a * 4 + 2) * NPIX + p];
        float d3 = bb[(a * 4 + 3) * NPIX + p];
        int ar_i = a / 3, sc_i = a - ar_i * 3;
        float arv = (ar_i == 0) ? 0.5f : ((ar_i == 1) ? 1.0f : 2.0f);
        float scv = (sc_i == 0) ? 128.f : ((sc_i == 1) ? 256.f : 512.f);
        float hr = sqrtf(arv);
        float wr = 1.0f / hr;
        float hs = hr * scv;
        float wsv = wr * scv;
        float bx1 = rintf(-wsv * 0.5f), by1 = rintf(-hs * 0.5f);
        float bx2 = rintf(wsv * 0.5f),  by2 = rintf(hs * 0.5f);
        float ax1 = x * 8.f + bx1, ay1 = y * 8.f + by1;
        float ax2 = x * 8.f + bx2, ay2 = y * 8.f + by2;
        float wa = ax2 - ax1, ha = ay2 - ay1;
        float cx = ax1 + 0.5f * wa, cy = ay1 + 0.5f * ha;
        float dw = fminf(d2, DW_CLIP_F), dh = fminf(d3, DW_CLIP_F);
        float px = d0 * wa + cx, py = d1 * ha + cy;
        float pw = expf(dw) * wa, ph = expf(dh) * ha;
        float x1 = px - 0.5f * pw, y1 = py - 0.5f * ph;
        float x2 = px + 0.5f * pw, y2 = py + 0.5f * ph;
        x1 = fminf(fmaxf(x1, 0.f), 1024.f);
        y1 = fminf(fmaxf(y1, 0.f), 1024.f);
        x2 = fminf(fmaxf(x2, 0.f), 1024.f);
        y2 = fminf(fmaxf(y2, 0.f), 1024.f);
        float bw = x2 - x1, bh = y2 - y1;
        valid = (bw >= 16.f) && (bh >= 16.f);
        selbox[r * 4 + 0] = x1; selbox[r * 4 + 1] = y1;
        selbox[r * 4 + 2] = x2; selbox[r * 4 + 3] = y2;
        selsc[r] = score;
    }
    ull bal = __ballot(valid);
    if (threadIdx.x == 0) validbits[blockIdx.x] = bal;
}

// ---------------------------------------------------------------- IOU suppression mask build
__global__ __launch_bounds__(256) void maskbuild_kernel(
    const float* __restrict__ selbox, ull* __restrict__ mask)
{
    __shared__ float jb0[64], jb1[64], jb2[64], jb3[64];
    const int jw = blockIdx.y;
    const int tid = threadIdx.x;
    const int i = blockIdx.x * 256 + tid;
    if (jw * 64 + 63 < blockIdx.x * 256) {
        if (i < PRENMS) mask[(size_t)i * MW + jw] = 0ull;
        return;
    }
    if (tid < 64) {
        int j = jw * 64 + tid;
        float x1 = 0.f, y1 = 0.f, x2 = 0.f, y2 = 0.f;
        if (j < PRENMS) {
            x1 = selbox[j * 4 + 0]; y1 = selbox[j * 4 + 1];
            x2 = selbox[j * 4 + 2]; y2 = selbox[j * 4 + 3];
        }
        jb0[tid] = x1; jb1[tid] = y1; jb2[tid] = x2; jb3[tid] = y2;
    }
    __syncthreads();
    if (i >= PRENMS) return;
    const float ix1 = selbox[i * 4 + 0], iy1 = selbox[i * 4 + 1];
    const float ix2 = selbox[i * 4 + 2], iy2 = selbox[i * 4 + 3];
    const float iarea = (ix2 - ix1) * (iy2 - iy1);
    ull word = 0ull;
    for (int b = 0; b < 64; ++b) {
        int j = jw * 64 + b;
        float xx1 = fmaxf(ix1, jb0[b]);
        float yy1 = fmaxf(iy1, jb1[b]);
        float xx2 = fminf(ix2, jb2[b]);
        float yy2 = fminf(iy2, jb3[b]);
        float iw = fmaxf(xx2 - xx1, 0.f);
        float ih = fmaxf(yy2 - yy1, 0.f);
        float inter = iw * ih;
        float jarea = (jb2[b] - jb0[b]) * (jb3[b] - jb1[b]);
        float iou = inter / (iarea + jarea - inter);
        if (j > i && iou > 0.7f) word |= (1ull << b);
    }
    mask[(size_t)i * MW + jw] = word;
}

// ---------------------------------------------------------------- chunked single-wave greedy NMS
__global__ __launch_bounds__(64) void nms_scan_kernel(
    const ull* __restrict__ validbits,
    const ull* __restrict__ mask,
    const float* __restrict__ selbox, const float* __restrict__ selsc,
    float* __restrict__ out)
{
    __shared__ int kept[POSTK];
    const int l = threadIdx.x;
    ull supp0 = ~validbits[l];
    ull supp1 = (l < 30) ? ~validbits[64 + l] : ~0ull;
    int nk = 0;
    ull ownrow_next = mask[(size_t)l * MW + 0];
    for (int wi = 0; wi < 94 && nk < POSTK; ++wi) {
        ull ownrow = ownrow_next;
        if (wi < 93) ownrow_next = mask[(size_t)((wi + 1) * 64 + l) * MW + (wi + 1)];
        ull wsup = (wi < 64) ? __shfl(supp0, wi) : __shfl(supp1, wi - 64);
        ull active = ~wsup;
        if (!active) continue;
        ull keptbits = 0ull;
        while (active && nk < POSTK) {
            int b = __builtin_ctzll(active);
            keptbits |= (1ull << b);
            if (l == 0) kept[nk] = wi * 64 + b;
            nk++;
            ull rowb = __shfl(ownrow, b);
            ull gt = (b == 63) ? 0ull : (~0ull << (b + 1));
            active &= gt & ~rowb;
        }
        while (keptbits) {
            int b0 = __builtin_ctzll(keptbits); keptbits &= keptbits - 1;
            int b1 = -1, b2 = -1, b3 = -1;
            if (keptbits) { b1 = __builtin_ctzll(keptbits); keptbits &= keptbits - 1; }
            if (keptbits) { b2 = __builtin_ctzll(keptbits); keptbits &= keptbits - 1; }
            if (keptbits) { b3 = __builtin_ctzll(keptbits); keptbits &= keptbits - 1; }
            const ull* r0 = mask + (size_t)(wi * 64 + b0) * MW;
            ull t0a = r0[l], t0b = (l < 30) ? r0[64 + l] : 0ull;
            ull t1a = 0, t1b = 0, t2a = 0, t2b = 0, t3a = 0, t3b = 0;
            if (b1 >= 0) { const ull* r1 = mask + (size_t)(wi * 64 + b1) * MW; t1a = r1[l]; t1b = (l < 30) ? r1[64 + l] : 0ull; }
            if (b2 >= 0) { const ull* r2 = mask + (size_t)(wi * 64 + b2) * MW; t2a = r2[l]; t2b = (l < 30) ? r2[64 + l] : 0ull; }
            if (b3 >= 0) { const ull* r3 = mask + (size_t)(wi * 64 + b3) * MW; t3a = r3[l]; t3b = (l < 30) ? r3[64 + l] : 0ull; }
            supp0 |= t0a | t1a | t2a | t3a;
            supp1 |= t0b | t1b | t2b | t3b;
        }
    }
    __syncthreads();
    for (int r = l; r < POSTK; r += 64) {
        if (r < nk) {
            int i = kept[r];
            out[r * 5 + 0] = selbox[i * 4 + 0];
            out[r * 5 + 1] = selbox[i * 4 + 1];
            out[r * 5 + 2] = selbox[i * 4 + 2];
            out[r * 5 + 3] = selbox[i * 4 + 3];
            out[r * 5 + 4] = selsc[i];
        } else {
            out[r * 5 + 0] = 0.f; out[r * 5 + 1] = 0.f;
            out[r * 5 + 2] = 0.f; out[r * 5 + 3] = 0.f;
            out[r * 5 + 4] = 0.f;
        }
    }
}

// ---------------------------------------------------------------- launch
extern "C" void kernel_launch(void* const* d_in, const int* in_sizes, int n_in,
                              void* d_out, int out_size, void* d_ws, size_t ws_size,
                              hipStream_t stream) {
    const float* feat    = (const float*)d_in[1];
    const float* conv_w  = (const float*)d_in[2];
    const float* conv_b  = (const float*)d_in[3];
    const float* cls_w   = (const float*)d_in[4];
    const float* cls_b   = (const float*)d_in[5];
    const float* bbox_w  = (const float*)d_in[6];
    const float* bbox_b  = (const float*)d_in[7];
    float* out = (float*)d_out;

    char* ws = (char*)d_ws;
    float*    part      = (float*)(ws + 0);                 // 33,554,432 (2 halves; half0 becomes rpn_feat)
    float*    rpn_feat  = part;                             // alias after combine
    float*    wt        = (float*)(ws + 33554432);          //  2,359,296
    float*    bb        = (float*)(ws + 35913728);          //  2,359,296
    float*    scores    = (float*)(ws + 38273024);          //    589,824
    unsigned* hist1     = (unsigned*)(ws + 38862848);       //     65,536
    unsigned* hist2     = (unsigned*)(ws + 38928384);       //    262,144
    unsigned* meta      = (unsigned*)(ws + 39190528);       //        256
    ull*      cand      = (ull*)(ws + 39190784);            //     65,536
    ull*      sorted    = (ull*)(ws + 39256320);            //     65,536
    ull*      fin       = (ull*)(ws + 39321856);            //     65,536
    float*    selbox    = (float*)(ws + 39387392);          //     96,256
    float*    selsc     = (float*)(ws + 39483648);          //     24,064
    ull*      validbits = (ull*)(ws + 39507712);            //        768
    ull*      mask      = (ull*)(ws + 39508480);            //  4,608,000  -> total 44,116,480

    wt_kernel<<<(2304 * 256 + 255) / 256, 256, 0, stream>>>(conv_w, wt);
    conv3x3_half_kernel<<<dim3(4, 16, 16), dim3(32, 8), 0, stream>>>(feat, wt, part);
    combine_kernel<<<4096, 256, 0, stream>>>(part, conv_b);
    heads_kernel<<<256, 256, 0, stream>>>(rpn_feat, cls_w, cls_b, bbox_w, bbox_b, scores, bb);

    {
        const float* sc_arg = scores;
        unsigned *h1 = hist1, *h2 = hist2, *mt = meta;
        ull *cd = cand, *so = sorted, *fi = fin;
        void* args[] = { (void*)&sc_arg, (void*)&h1, (void*)&h2, (void*)&mt,
                         (void*)&cd, (void*)&so, (void*)&fi };
        hipLaunchCooperativeKernel((void*)select_kernel, dim3(64), dim3(1024),
                                   args, 0, stream);
    }

    decode_kernel<<<94, 64, 0, stream>>>(fin, bb, selbox, selsc, validbits);
    maskbuild_kernel<<<dim3(24, 94), 256, 0, stream>>>(selbox, mask);
    nms_scan_kernel<<<1, 64, 0, stream>>>(validbits, mask, selbox, selsc, out);
}

// Round 7
// 530.552 us; speedup vs baseline: 2.6411x; 1.3159x over previous
//
#include <hip/hip_runtime.h>

#define HW 128
#define NPIX 16384      // 128*128
#define CIN 256
#define NSC 147456      // NPIX*9
#define PRENMS 6000
#define POSTK 300
#define DW_CLIP_F 4.135166556742356f
#define MW 96           // u64 words per mask row
typedef unsigned long long ull;

// ---------------------------------------------------------------- weight transpose + scratch zero
// w: [co=256][k=2304] -> wt: [k=2304][co=256]; also zeroes hist1+hist2+meta
// (contiguous, 82 KB) and validbits (94 u64) -- replaces the zero_kernel dispatch.
__global__ void wt_kernel(const float* __restrict__ w, float* __restrict__ wt,
                          unsigned* __restrict__ zp, ull* __restrict__ vb) {
    int i = blockIdx.x * 256 + threadIdx.x;
    if (i < 2304 * 256) {
        int k = i >> 8, co = i & 255;
        wt[i] = w[co * 2304 + k];
    }
    if (i < 16384 + 65536 + 64) zp[i] = 0u;
    if (i < 94) vb[i] = 0ull;
}

// ---------------------------------------------------------------- 3x3 conv, K-split halves
// EXACT R1 structure (best measured: 241us, VALUBusy ~61%, conflicts 0, bit-exact).
// 32x8 spatial tile, 34-float row stride, co=32 per block, ci-chunk 16,
// s_load (SMEM) weight path. R2/R4/R5 conv experiments all regressed.
__global__ __launch_bounds__(256) void conv3x3_half_kernel(
    const float* __restrict__ feat, const float* __restrict__ wt,
    float* __restrict__ part)
{
    __shared__ float in_s[16 * 340];    // 16 ci * (10 rows * 34 floats) = 21760 B
    const int tx = threadIdx.x;         // 0..31
    const int ty = threadIdx.y;         // 0..7
    const int x0 = blockIdx.x * 32;
    const int y0 = blockIdx.y * 8;
    const int h  = blockIdx.z >> 3;
    const int co0 = (blockIdx.z & 7) << 5;
    const int tid = ty * 32 + tx;

    // staging geometry computed ONCE (patch 10 x 34 = 340 entries, 256 threads)
    const int yy1 = tid / 34, xx1 = tid - yy1 * 34;
    const int t2 = tid + 256;
    const int yy2 = t2 / 34, xx2 = t2 - yy2 * 34;
    const int gy1 = y0 + yy1 - 1, gx1 = x0 + xx1 - 1;
    const int gy2 = y0 + yy2 - 1, gx2 = x0 + xx2 - 1;
    const bool p1 = ((unsigned)gy1 < 128u) && ((unsigned)gx1 < 128u);
    const bool p2 = (tid < 84) && ((unsigned)gy2 < 128u) && ((unsigned)gx2 < 128u);
    const int a1 = p1 ? (gy1 * 128 + gx1) : 0;
    const int a2 = p2 ? (gy2 * 128 + gx2) : 0;

    float acc[32];
#pragma unroll
    for (int i = 0; i < 32; ++i) acc[i] = 0.f;

    const float* fh = feat + h * 128 * NPIX;
    const float* wh = wt + h * 128 * 9 * 256;

    for (int s = 0; s < 8; ++s) {
        __syncthreads();
        const float* fbase = fh + s * 16 * NPIX;
#pragma unroll
        for (int ci = 0; ci < 16; ++ci) {
            float t = fbase[ci * NPIX + a1];
            in_s[ci * 340 + tid] = p1 ? t : 0.f;
        }
        if (tid < 84) {
#pragma unroll
            for (int ci = 0; ci < 16; ++ci) {
                float t = fbase[ci * NPIX + a2];
                in_s[ci * 340 + 256 + tid] = p2 ? t : 0.f;
            }
        }
        __syncthreads();
        const float* ws0 = wh + s * 16 * 9 * 256 + co0;
#pragma unroll 2
        for (int ci = 0; ci < 16; ++ci) {
            const float* wrow = ws0 + ci * 9 * 256;
#pragma unroll
            for (int t = 0; t < 9; ++t) {
                const int ky = t / 3, kx = t - ky * 3;
                float v = in_s[ci * 340 + (ty + ky) * 34 + (tx + kx)];
                const float* wp = wrow + t * 256;   // wave-uniform -> s_load_dwordx16
#pragma unroll
                for (int co = 0; co < 32; ++co)
                    acc[co] = fmaf(v, wp[co], acc[co]);
            }
        }
    }
    float* po = part + h * (CIN * NPIX) + co0 * NPIX + (y0 + ty) * 128 + (x0 + tx);
#pragma unroll
    for (int co = 0; co < 32; ++co)
        po[co * NPIX] = acc[co];
}

// ---------------------------------------------------------------- 1x1 heads (+ fused combine)
// rpn_feat is consumed ONLY here, so the combine (part0+part1+bias, relu) is
// computed inline with the exact expression/order of the old combine_kernel
// -> bit-exact. 4 waves/block, each wave owns a 12-slot slice of the 45 outputs.
__global__ __launch_bounds__(256) void heads_kernel(
    const float* __restrict__ part, const float* __restrict__ conv_b,
    const float* __restrict__ cls_w, const float* __restrict__ cls_b,
    const float* __restrict__ bbox_w, const float* __restrict__ bbox_b,
    float* __restrict__ scores, float* __restrict__ bb)
{
    __shared__ float wl[256][48];   // [ci][slot], 0-8 = cls, 9-44 = bbox, 45-47 = 0
    const int tid = threadIdx.x;
    for (int e = tid; e < 256 * 48; e += 256) {
        int ci = e / 48, s = e - ci * 48;
        wl[ci][s] = (s < 9) ? cls_w[s * CIN + ci]
                  : (s < 45) ? bbox_w[(s - 9) * CIN + ci] : 0.f;
    }
    __syncthreads();

    const int lane = tid & 63;
    const int sg   = tid >> 6;          // slot group 0..3
    const int p    = blockIdx.x * 64 + lane;
    const int s0   = sg * 12;
    const int ns   = (sg == 3) ? 9 : 12;

    float acc[12];
#pragma unroll
    for (int i = 0; i < 12; ++i) acc[i] = 0.f;

    const float* part1 = part + CIN * NPIX;
#pragma unroll 4
    for (int ci = 0; ci < CIN; ++ci) {
        float a = part[ci * NPIX + p];
        float c = part1[ci * NPIX + p];
        float v = fmaxf(a + c + conv_b[ci], 0.f);   // verbatim combine expr
        const float* wr = &wl[ci][s0];
#pragma unroll
        for (int j = 0; j < 12; ++j)
            acc[j] = fmaf(v, wr[j], acc[j]);
    }
    for (int j = 0; j < ns; ++j) {
        int s = s0 + j;
        if (s < 9) {
            float sc = acc[j] + cls_b[s];
            scores[p * 9 + s] = 1.0f / (1.0f + expf(-sc));
        } else {
            bb[(s - 9) * NPIX + p] = acc[j] + bbox_b[s - 9];
        }
    }
}

// ---------------------------------------------------------------- top-k select: histograms
__global__ __launch_bounds__(1024) void hist1_kernel(const float* __restrict__ scores,
                                                     unsigned* __restrict__ hist1) {
    __shared__ unsigned h[16384];
    const int tid = threadIdx.x;
    for (int i = tid; i < 16384; i += 1024) h[i] = 0u;
    __syncthreads();
    for (int i = blockIdx.x * 1024 + tid; i < NSC; i += gridDim.x * 1024) {
        unsigned bits = __float_as_uint(scores[i]);
        atomicAdd(&h[bits >> 16], 1u);
    }
    __syncthreads();
    for (int i = tid; i < 16384; i += 1024) {
        unsigned c = h[i];
        if (c) atomicAdd(&hist1[i], c);
    }
}

__global__ __launch_bounds__(1024) void scan1_kernel(const unsigned* __restrict__ hist,
                                                     unsigned* __restrict__ meta) {
    __shared__ unsigned ssum[1024];
    const int t = threadIdx.x;
    unsigned local[16];
    unsigned s = 0;
#pragma unroll
    for (int i = 0; i < 16; ++i) { local[i] = hist[t * 16 + i]; s += local[i]; }
    ssum[t] = s;
    __syncthreads();
    for (int off = 1; off < 1024; off <<= 1) {
        unsigned v = ssum[t] + ((t + off < 1024) ? ssum[t + off] : 0u);
        __syncthreads();
        ssum[t] = v;
        __syncthreads();
    }
    unsigned run = ssum[t] - s;
#pragma unroll
    for (int i = 15; i >= 0; --i) {
        unsigned nb = run + local[i];
        if (nb >= (unsigned)PRENMS && run < (unsigned)PRENMS) {
            meta[1] = (unsigned)(t * 16 + i);
            meta[2] = run;
        }
        run = nb;
    }
}

__global__ void hist2_kernel(const float* __restrict__ scores, const unsigned* __restrict__ meta,
                             unsigned* __restrict__ hist2) {
    int i = blockIdx.x * 256 + threadIdx.x;
    if (i < NSC) {
        unsigned bits = __float_as_uint(scores[i]);
        if ((bits >> 16) == meta[1]) atomicAdd(&hist2[bits & 0xFFFFu], 1u);
    }
}

__global__ __launch_bounds__(1024) void scan2_kernel(const unsigned* __restrict__ hist2,
                                                     unsigned* __restrict__ meta) {
    __shared__ unsigned ssum[1024];
    const int t = threadIdx.x;
    const unsigned need = (unsigned)PRENMS - meta[2];
    unsigned s = 0;
    for (int i = 0; i < 64; ++i) s += hist2[t * 64 + i];
    ssum[t] = s;
    __syncthreads();
    for (int off = 1; off < 1024; off <<= 1) {
        unsigned v = ssum[t] + ((t + off < 1024) ? ssum[t + off] : 0u);
        __syncthreads();
        ssum[t] = v;
        __syncthreads();
    }
    unsigned run = ssum[t] - s;
    for (int i = 63; i >= 0; --i) {
        unsigned h = hist2[t * 64 + i];
        unsigned nb = run + h;
        if (nb >= need && run < need) {
            meta[3] = (meta[1] << 16) | (unsigned)(t * 64 + i);
        }
        run = nb;
    }
}

// wave-aggregated compaction: 1 atomic per wave
__global__ void compact_kernel(const float* __restrict__ scores, unsigned* __restrict__ meta,
                               ull* __restrict__ cand) {
    int i = blockIdx.x * 256 + threadIdx.x;
    unsigned bits = (i < NSC) ? __float_as_uint(scores[i]) : 0u;
    bool pred = (i < NSC) && (bits >= meta[3]);
    ull bal = __ballot(pred);
    int lane = threadIdx.x & 63;
    unsigned cnt = (unsigned)__popcll(bal);
    unsigned base = 0;
    if (lane == 0 && cnt) base = atomicAdd(&meta[0], cnt);
    base = __shfl(base, 0);
    if (pred) {
        unsigned off = (unsigned)__popcll(bal & ((1ull << lane) - 1ull));
        unsigned pos = base + off;
        if (pos < 8192u)
            cand[pos] = ((ull)bits << 32) | (unsigned)(~i);
    }
}

// ---------------------------------------------------------------- parallel sort: 4 local sorts
__global__ __launch_bounds__(1024) void sortA_kernel(const ull* __restrict__ cand,
                                                     const unsigned* __restrict__ meta,
                                                     ull* __restrict__ sorted) {
    __shared__ ull keys[2048];
    const int tid = threadIdx.x;
    const int base = blockIdx.x * 2048;
    const int n = min((int)meta[0], 8192);
    for (int i = tid; i < 2048; i += 1024) {
        int g = base + i;
        keys[i] = (g < n) ? cand[g] : (ull)(8191 - g);
    }
    __syncthreads();
    for (int k = 2; k <= 2048; k <<= 1) {
        for (int j = k >> 1; j >= 1; j >>= 1) {
            int s = tid;
            int i = ((s & ~(j - 1)) << 1) | (s & (j - 1));
            int p = i | j;
            ull a = keys[i], c = keys[p];
            bool desc = ((i & k) == 0);
            bool sw = desc ? (a < c) : (a > c);
            if (sw) { keys[i] = c; keys[p] = a; }
            __syncthreads();
        }
    }
    for (int i = tid; i < 2048; i += 1024) sorted[base + i] = keys[i];
}

// ---------------------------------------------------------------- rank-merge + fused decode
// Each thread computes its global rank (verbatim merge_kernel); when rank<6000
// it decodes the box inline (verbatim decode formulas) and sets the valid bit
// via atomicOr (commutative; validbits pre-zeroed in wt_kernel). fin removed.
__global__ __launch_bounds__(256) void merge_decode_kernel(
    const ull* __restrict__ sorted, const float* __restrict__ bb,
    float* __restrict__ selbox, float* __restrict__ selsc,
    ull* __restrict__ validbits)
{
    const int g = blockIdx.x * 256 + threadIdx.x;   // 32 blocks -> 8192
    ull x = sorted[g];
    const int c = g >> 11;
    int rank = g & 2047;
#pragma unroll
    for (int cc = 0; cc < 4; ++cc) {
        if (cc == c) continue;
        const ull* arr = sorted + cc * 2048;
        int lo = 0, hi = 2048;
        while (lo < hi) { int mid = (lo + hi) >> 1; if (arr[mid] > x) lo = mid + 1; else hi = mid; }
        rank += lo;
    }
    if (rank < PRENMS) {
        const int r = rank;
        unsigned sbits = (unsigned)(x >> 32);
        unsigned idx = ~(unsigned)(x & 0xFFFFFFFFull);
        float score = __uint_as_float(sbits);
        int p = (int)(idx / 9u);
        int a = (int)(idx - (unsigned)p * 9u);
        int y = p >> 7, xx = p & 127;
        float d0 = bb[(a * 4 + 0) * NPIX + p];
        float d1 = bb[(a * 4 + 1) * NPIX + p];
        float d2 = bb[(a * 4 + 2) * NPIX + p];
        float d3 = bb[(a * 4 + 3) * NPIX + p];
        int ar_i = a / 3, sc_i = a - ar_i * 3;
        float arv = (ar_i == 0) ? 0.5f : ((ar_i == 1) ? 1.0f : 2.0f);
        float scv = (sc_i == 0) ? 128.f : ((sc_i == 1) ? 256.f : 512.f);
        float hr = sqrtf(arv);
        float wr = 1.0f / hr;
        float hs = hr * scv;
        float wsv = wr * scv;
        float bx1 = rintf(-wsv * 0.5f), by1 = rintf(-hs * 0.5f);
        float bx2 = rintf(wsv * 0.5f),  by2 = rintf(hs * 0.5f);
        float ax1 = xx * 8.f + bx1, ay1 = y * 8.f + by1;
        float ax2 = xx * 8.f + bx2, ay2 = y * 8.f + by2;
        float wa = ax2 - ax1, ha = ay2 - ay1;
        float cx = ax1 + 0.5f * wa, cy = ay1 + 0.5f * ha;
        float dw = fminf(d2, DW_CLIP_F), dh = fminf(d3, DW_CLIP_F);
        float px = d0 * wa + cx, py = d1 * ha + cy;
        float pw = expf(dw) * wa, ph = expf(dh) * ha;
        float x1 = px - 0.5f * pw, y1 = py - 0.5f * ph;
        float x2 = px + 0.5f * pw, y2 = py + 0.5f * ph;
        x1 = fminf(fmaxf(x1, 0.f), 1024.f);
        y1 = fminf(fmaxf(y1, 0.f), 1024.f);
        x2 = fminf(fmaxf(x2, 0.f), 1024.f);
        y2 = fminf(fmaxf(y2, 0.f), 1024.f);
        float bw = x2 - x1, bh = y2 - y1;
        bool valid = (bw >= 16.f) && (bh >= 16.f);
        selbox[r * 4 + 0] = x1; selbox[r * 4 + 1] = y1;
        selbox[r * 4 + 2] = x2; selbox[r * 4 + 3] = y2;
        selsc[r] = score;
        if (valid) atomicOr(&validbits[r >> 6], 1ull << (r & 63));
    }
}

// ---------------------------------------------------------------- IOU suppression mask build
__global__ __launch_bounds__(256) void maskbuild_kernel(
    const float* __restrict__ selbox, ull* __restrict__ mask)
{
    __shared__ float jb0[64], jb1[64], jb2[64], jb3[64];
    const int jw = blockIdx.y;
    const int tid = threadIdx.x;
    const int i = blockIdx.x * 256 + tid;
    if (jw * 64 + 63 < blockIdx.x * 256) {
        if (i < PRENMS) mask[(size_t)i * MW + jw] = 0ull;
        return;
    }
    if (tid < 64) {
        int j = jw * 64 + tid;
        float x1 = 0.f, y1 = 0.f, x2 = 0.f, y2 = 0.f;
        if (j < PRENMS) {
            x1 = selbox[j * 4 + 0]; y1 = selbox[j * 4 + 1];
            x2 = selbox[j * 4 + 2]; y2 = selbox[j * 4 + 3];
        }
        jb0[tid] = x1; jb1[tid] = y1; jb2[tid] = x2; jb3[tid] = y2;
    }
    __syncthreads();
    if (i >= PRENMS) return;
    const float ix1 = selbox[i * 4 + 0], iy1 = selbox[i * 4 + 1];
    const float ix2 = selbox[i * 4 + 2], iy2 = selbox[i * 4 + 3];
    const float iarea = (ix2 - ix1) * (iy2 - iy1);
    ull word = 0ull;
    for (int b = 0; b < 64; ++b) {
        int j = jw * 64 + b;
        float xx1 = fmaxf(ix1, jb0[b]);
        float yy1 = fmaxf(iy1, jb1[b]);
        float xx2 = fminf(ix2, jb2[b]);
        float yy2 = fminf(iy2, jb3[b]);
        float iw = fmaxf(xx2 - xx1, 0.f);
        float ih = fmaxf(yy2 - yy1, 0.f);
        float inter = iw * ih;
        float jarea = (jb2[b] - jb0[b]) * (jb3[b] - jb1[b]);
        float iou = inter / (iarea + jarea - inter);
        if (j > i && iou > 0.7f) word |= (1ull << b);
    }
    mask[(size_t)i * MW + jw] = word;
}

// ---------------------------------------------------------------- chunked single-wave greedy NMS
__global__ __launch_bounds__(64) void nms_scan_kernel(
    const ull* __restrict__ validbits,
    const ull* __restrict__ mask,
    const float* __restrict__ selbox, const float* __restrict__ selsc,
    float* __restrict__ out)
{
    __shared__ int kept[POSTK];
    const int l = threadIdx.x;
    ull supp0 = ~validbits[l];
    ull supp1 = (l < 30) ? ~validbits[64 + l] : ~0ull;
    int nk = 0;
    ull ownrow_next = mask[(size_t)l * MW + 0];
    for (int wi = 0; wi < 94 && nk < POSTK; ++wi) {
        ull ownrow = ownrow_next;
        if (wi < 93) ownrow_next = mask[(size_t)((wi + 1) * 64 + l) * MW + (wi + 1)];
        ull wsup = (wi < 64) ? __shfl(supp0, wi) : __shfl(supp1, wi - 64);
        ull active = ~wsup;
        if (!active) continue;
        ull keptbits = 0ull;
        while (active && nk < POSTK) {
            int b = __builtin_ctzll(active);
            keptbits |= (1ull << b);
            if (l == 0) kept[nk] = wi * 64 + b;
            nk++;
            ull rowb = __shfl(ownrow, b);
            ull gt = (b == 63) ? 0ull : (~0ull << (b + 1));
            active &= gt & ~rowb;
        }
        while (keptbits) {
            int b0 = __builtin_ctzll(keptbits); keptbits &= keptbits - 1;
            int b1 = -1, b2 = -1, b3 = -1;
            if (keptbits) { b1 = __builtin_ctzll(keptbits); keptbits &= keptbits - 1; }
            if (keptbits) { b2 = __builtin_ctzll(keptbits); keptbits &= keptbits - 1; }
            if (keptbits) { b3 = __builtin_ctzll(keptbits); keptbits &= keptbits - 1; }
            const ull* r0 = mask + (size_t)(wi * 64 + b0) * MW;
            ull t0a = r0[l], t0b = (l < 30) ? r0[64 + l] : 0ull;
            ull t1a = 0, t1b = 0, t2a = 0, t2b = 0, t3a = 0, t3b = 0;
            if (b1 >= 0) { const ull* r1 = mask + (size_t)(wi * 64 + b1) * MW; t1a = r1[l]; t1b = (l < 30) ? r1[64 + l] : 0ull; }
            if (b2 >= 0) { const ull* r2 = mask + (size_t)(wi * 64 + b2) * MW; t2a = r2[l]; t2b = (l < 30) ? r2[64 + l] : 0ull; }
            if (b3 >= 0) { const ull* r3 = mask + (size_t)(wi * 64 + b3) * MW; t3a = r3[l]; t3b = (l < 30) ? r3[64 + l] : 0ull; }
            supp0 |= t0a | t1a | t2a | t3a;
            supp1 |= t0b | t1b | t2b | t3b;
        }
    }
    __syncthreads();
    for (int r = l; r < POSTK; r += 64) {
        if (r < nk) {
            int i = kept[r];
            out[r * 5 + 0] = selbox[i * 4 + 0];
            out[r * 5 + 1] = selbox[i * 4 + 1];
            out[r * 5 + 2] = selbox[i * 4 + 2];
            out[r * 5 + 3] = selbox[i * 4 + 3];
            out[r * 5 + 4] = selsc[i];
        } else {
            out[r * 5 + 0] = 0.f; out[r * 5 + 1] = 0.f;
            out[r * 5 + 2] = 0.f; out[r * 5 + 3] = 0.f;
            out[r * 5 + 4] = 0.f;
        }
    }
}

// ---------------------------------------------------------------- launch
extern "C" void kernel_launch(void* const* d_in, const int* in_sizes, int n_in,
                              void* d_out, int out_size, void* d_ws, size_t ws_size,
                              hipStream_t stream) {
    const float* feat    = (const float*)d_in[1];
    const float* conv_w  = (const float*)d_in[2];
    const float* conv_b  = (const float*)d_in[3];
    const float* cls_w   = (const float*)d_in[4];
    const float* cls_b   = (const float*)d_in[5];
    const float* bbox_w  = (const float*)d_in[6];
    const float* bbox_b  = (const float*)d_in[7];
    float* out = (float*)d_out;

    char* ws = (char*)d_ws;
    float*    part      = (float*)(ws + 0);                 // 33,554,432 (2 halves)
    float*    wt        = (float*)(ws + 33554432);          //  2,359,296
    float*    bb        = (float*)(ws + 35913728);          //  2,359,296
    float*    scores    = (float*)(ws + 38273024);          //    589,824
    unsigned* hist1     = (unsigned*)(ws + 38862848);       //     65,536
    unsigned* hist2     = (unsigned*)(ws + 38928384);       //    262,144
    unsigned* meta      = (unsigned*)(ws + 39190528);       //        256
    ull*      cand      = (ull*)(ws + 39190784);            //     65,536
    ull*      sorted    = (ull*)(ws + 39256320);            //     65,536
    ull*      fin       = (ull*)(ws + 39321856);            //     65,536 (unused now)
    float*    selbox    = (float*)(ws + 39387392);          //     96,256
    float*    selsc     = (float*)(ws + 39483648);          //     24,064
    ull*      validbits = (ull*)(ws + 39507712);            //        768
    ull*      mask      = (ull*)(ws + 39508480);            //  4,608,000  -> total 44,116,480
    (void)fin;

    wt_kernel<<<2304, 256, 0, stream>>>(conv_w, wt, hist1, validbits);
    conv3x3_half_kernel<<<dim3(4, 16, 16), dim3(32, 8), 0, stream>>>(feat, wt, part);
    heads_kernel<<<256, 256, 0, stream>>>(part, conv_b, cls_w, cls_b, bbox_w, bbox_b, scores, bb);
    hist1_kernel<<<64, 1024, 0, stream>>>(scores, hist1);
    scan1_kernel<<<1, 1024, 0, stream>>>(hist1, meta);
    hist2_kernel<<<(NSC + 255) / 256, 256, 0, stream>>>(scores, meta, hist2);
    scan2_kernel<<<1, 1024, 0, stream>>>(hist2, meta);
    compact_kernel<<<(NSC + 255) / 256, 256, 0, stream>>>(scores, meta, cand);
    sortA_kernel<<<4, 1024, 0, stream>>>(cand, meta, sorted);
    merge_decode_kernel<<<32, 256, 0, stream>>>(sorted, bb, selbox, selsc, validbits);
    maskbuild_kernel<<<dim3(24, 94), 256, 0, stream>>>(selbox, mask);
    nms_scan_kernel<<<1, 64, 0, stream>>>(validbits, mask, selbox, selsc, out);
}